// Round 1
// baseline (94.379 us; speedup 1.0000x reference)
//
#include <hip/hip_runtime.h>
#include <math.h>

// Problem constants (from setup_inputs: batch=1024, dim_z=32, n_samples=32, agg_size=256)
#define B    1024
#define D    32
#define NS   32
#define AGG  256
#define NC   (B / AGG)      // 4 chunks
#define M    (AGG * NS)     // 8192 samples per chunk
#define JB   1024           // samples per block
#define NJB  (M / JB)       // 8 j-blocks per (c,k)
#define TJ   (JB / 256)     // 4 samples per thread
#define NBLK (NC * D * NJB) // 1024 blocks

// Param table layout in ws (after 4KB partials): float4[(c*D+k)*AGG + i] =
//   { mu, -0.5*log2e*exp(-lv), -0.5*log2e*lv, exp(0.5*lv) }
__global__ __launch_bounds__(256) void ksetup(const float* __restrict__ mean,
                                              const float* __restrict__ logvar,
                                              float4* __restrict__ params)
{
    constexpr float LOG2E = 1.4426950408889634f;
    const int id = blockIdx.x * 256 + threadIdx.x;  // ((c*D+k)*AGG + i)
    const int i  = id & (AGG - 1);
    const int ck = id >> 8;          // c*D + k  (AGG=256)
    const int k  = ck & (D - 1);
    const int c  = ck >> 5;          // D=32
    const int row = c * AGG + i;
    const float mu = mean[row * D + k];
    const float lv = logvar[row * D + k];
    const float ev = exp2f(-lv * LOG2E);             // exp(-lv)
    params[id] = make_float4(mu, -0.5f * LOG2E * ev, -0.5f * LOG2E * lv,
                             exp2f(0.5f * LOG2E * lv));
}

template <bool USE_GP>
__global__ __launch_bounds__(256) void kmain(const float* __restrict__ mean,
                                             const float* __restrict__ logvar,
                                             const float* __restrict__ eps,
                                             const float4* __restrict__ params,
                                             float* __restrict__ partial)
{
    constexpr float LOG2E = 1.4426950408889634f;
    constexpr float LN2   = 0.6931471805599453f;
    const int bid = blockIdx.x;
    const int c   = bid / (D * NJB);
    const int rem = bid - c * (D * NJB);
    const int k   = rem / NJB;
    const int jb  = rem - k * NJB;
    const int j0  = jb * JB;
    const int t   = threadIdx.x;

    __shared__ float4 prm[AGG];
    const float4* __restrict__ pk = USE_GP ? (params + (c * D + k) * AGG) : nullptr;
    if (!USE_GP) {
        const int row  = c * AGG + t;     // thread t sets up component i=t
        const float mu = mean[row * D + k];
        const float lv = logvar[row * D + k];
        const float ev = exp2f(-lv * LOG2E);
        prm[t] = make_float4(mu, -0.5f * LOG2E * ev, -0.5f * LOG2E * lv,
                             exp2f(0.5f * LOG2E * lv));
        __syncthreads();
    }

    // z for this thread's TJ samples (z2 flat layout == eps flat layout)
    float zv[TJ], acc[TJ];
#pragma unroll
    for (int u = 0; u < TJ; ++u) {
        const int j = j0 + t + 256 * u;
        const float4 p = USE_GP ? pk[j >> 5] : prm[j >> 5];  // component row j/32
        const float e  = eps[(size_t)(c * M + j) * D + k];
        zv[u]  = fmaf(e, p.w, p.x);   // mean + eps*std
        acc[u] = 0.f;
    }

    // Main pairwise loop: sum over 256 components. pk[i] is wave-uniform -> s_load.
#pragma unroll 4
    for (int i = 0; i < AGG; ++i) {
        const float4 p = USE_GP ? pk[i] : prm[i];
#pragma unroll
        for (int u = 0; u < TJ; ++u) {
            const float d = zv[u] - p.x;
            acc[u] += exp2f(fmaf(d * d, p.y, p.z));  // exp(-0.5*((z-mu)^2*e^-lv + lv))
        }
    }

    // per-thread contribution: ln(sum_i) + 0.5*z^2  (constants folded in final kernel)
    float r = 0.f;
#pragma unroll
    for (int u = 0; u < TJ; ++u)
        r += LN2 * log2f(acc[u]) + 0.5f * zv[u] * zv[u];

    // block reduction (deterministic)
    for (int off = 32; off > 0; off >>= 1) r += __shfl_down(r, off, 64);
    __shared__ float wsum[4];
    if ((t & 63) == 0) wsum[t >> 6] = r;
    __syncthreads();
    if (t == 0) partial[bid] = (wsum[0] + wsum[1]) + (wsum[2] + wsum[3]);
}

__global__ __launch_bounds__(256) void kfinal(const float* __restrict__ partial,
                                              float* __restrict__ out)
{
    const int t = threadIdx.x;
    double s = 0.0;
#pragma unroll
    for (int i = 0; i < NBLK / 256; ++i) s += (double)partial[i * 256 + t];
    __shared__ double sd[256];
    sd[t] = s;
    __syncthreads();
    for (int off = 128; off > 0; off >>= 1) {
        if (t < off) sd[t] += sd[t + off];
        __syncthreads();
    }
    if (t == 0) {
        // out = total/(nc*M) - D*ln(256)
        out[0] = (float)(sd[0] * (1.0 / (double)(NC * M))
                         - (double)D * 5.545177444479562);
    }
}

extern "C" void kernel_launch(void* const* d_in, const int* in_sizes, int n_in,
                              void* d_out, int out_size, void* d_ws, size_t ws_size,
                              hipStream_t stream)
{
    const float* mean   = (const float*)d_in[0];
    const float* logvar = (const float*)d_in[1];
    const float* eps    = (const float*)d_in[2];
    float* out = (float*)d_out;

    float*  partial = (float*)d_ws;                       // NBLK floats = 4KB
    float4* params  = (float4*)((char*)d_ws + 4096);      // 512KB param table
    const bool use_gp = ws_size >= (size_t)4096 + sizeof(float4) * NC * D * AGG;

    if (use_gp) {
        ksetup<<<(NC * D * AGG) / 256, 256, 0, stream>>>(mean, logvar, params);
        kmain<true><<<NBLK, 256, 0, stream>>>(mean, logvar, eps, params, partial);
    } else {
        kmain<false><<<NBLK, 256, 0, stream>>>(mean, logvar, eps, nullptr, partial);
    }
    kfinal<<<1, 256, 0, stream>>>(partial, out);
}

// Round 2
// 55.785 us; speedup vs baseline: 1.6918x; 1.6918x over previous
//
#include <hip/hip_runtime.h>
#include <math.h>

// Problem constants (from setup_inputs: batch=1024, dim_z=32, n_samples=32, agg_size=256)
#define B    1024
#define D    32
#define NS   32
#define AGG  256
#define NC   (B / AGG)      // 4 chunks
#define M    (AGG * NS)     // 8192 samples per chunk
#define JB   1024           // samples per block
#define NJB  (M / JB)       // 8 j-blocks per (c,k)
#define TJ   (JB / 256)     // 4 samples per thread
#define NBLK (NC * D * NJB) // 1024 blocks

// Param table in ws (after 4KB partials): float4[(c*D+k)*AGG + i] = {A, B, C, pad}
// with  arg(z) = A*z^2 + B*z + C  =  -0.5*log2e*((z-mu)^2*exp(-lv) + lv)
//   A = -0.5*log2e*exp(-lv)
//   B =  log2e*mu*exp(-lv)
//   C = -0.5*log2e*(mu^2*exp(-lv) + lv)
__global__ __launch_bounds__(256) void ksetup(const float* __restrict__ mean,
                                              const float* __restrict__ logvar,
                                              float4* __restrict__ params)
{
    constexpr float LOG2E = 1.4426950408889634f;
    const int id = blockIdx.x * 256 + threadIdx.x;  // ((c*D+k)*AGG + i)
    const int i  = id & (AGG - 1);
    const int ck = id >> 8;          // c*D + k  (AGG=256)
    const int k  = ck & (D - 1);
    const int c  = ck >> 5;          // D=32
    const int row = c * AGG + i;
    const float mu = mean[row * D + k];
    const float lv = logvar[row * D + k];
    const float ev = __builtin_amdgcn_exp2f(-lv * LOG2E);   // exp(-lv), lv in ~[-5,5]: safe
    const float A  = -0.5f * LOG2E * ev;
    const float Bc = LOG2E * mu * ev;
    const float Cc = -0.5f * LOG2E * fmaf(mu * mu, ev, lv);
    params[id] = make_float4(A, Bc, Cc, 0.f);
}

template <bool USE_GP>
__global__ __launch_bounds__(256) void kmain(const float* __restrict__ mean,
                                             const float* __restrict__ logvar,
                                             const float* __restrict__ eps,
                                             const float4* __restrict__ params,
                                             float* __restrict__ partial)
{
    constexpr float LOG2E = 1.4426950408889634f;
    constexpr float LN2   = 0.6931471805599453f;
    const int bid = blockIdx.x;
    const int c   = bid / (D * NJB);
    const int rem = bid - c * (D * NJB);
    const int k   = rem / NJB;
    const int jb  = rem - k * NJB;
    const int j0  = jb * JB;
    const int t   = threadIdx.x;

    __shared__ float4 prm[AGG];
    const float4* __restrict__ pk = USE_GP ? (params + (c * D + k) * AGG) : nullptr;
    if (!USE_GP) {
        const int row  = c * AGG + t;     // thread t sets up component i=t
        const float mu = mean[row * D + k];
        const float lv = logvar[row * D + k];
        const float ev = __builtin_amdgcn_exp2f(-lv * LOG2E);
        prm[t] = make_float4(-0.5f * LOG2E * ev, LOG2E * mu * ev,
                             -0.5f * LOG2E * fmaf(mu * mu, ev, lv), 0.f);
        __syncthreads();
    }

    // z for this thread's TJ samples (z2 flat layout == eps flat layout)
    float zv[TJ], acc[TJ];
#pragma unroll
    for (int u = 0; u < TJ; ++u) {
        const int j   = j0 + t + 256 * u;
        const int row = c * AGG + (j >> 5);          // this sample's own component
        const float mu = mean[row * D + k];
        const float lv = logvar[row * D + k];
        const float sd = __builtin_amdgcn_exp2f(0.5f * LOG2E * lv);  // exp(0.5*lv)
        const float e  = eps[(size_t)(c * M + j) * D + k];
        zv[u]  = fmaf(e, sd, mu);
        acc[u] = 0.f;
    }

    // Main pairwise loop over 256 components. pk[i] is wave-uniform -> scalar loads.
    // Per (i,u): 2 v_fma + 1 v_add + 1 v_exp.
#pragma unroll 8
    for (int i = 0; i < AGG; ++i) {
        const float4 p = USE_GP ? pk[i] : prm[i];
#pragma unroll
        for (int u = 0; u < TJ; ++u) {
            const float arg = fmaf(fmaf(p.x, zv[u], p.y), zv[u], p.z);
            acc[u] += __builtin_amdgcn_exp2f(arg);
        }
    }

    // per-thread contribution: ln(sum_i) + 0.5*z^2  (constants folded in kfinal)
    float r = 0.f;
#pragma unroll
    for (int u = 0; u < TJ; ++u)
        r += LN2 * log2f(acc[u]) + 0.5f * zv[u] * zv[u];

    // block reduction (deterministic)
    for (int off = 32; off > 0; off >>= 1) r += __shfl_down(r, off, 64);
    __shared__ float wsum[4];
    if ((t & 63) == 0) wsum[t >> 6] = r;
    __syncthreads();
    if (t == 0) partial[bid] = (wsum[0] + wsum[1]) + (wsum[2] + wsum[3]);
}

__global__ __launch_bounds__(256) void kfinal(const float* __restrict__ partial,
                                              float* __restrict__ out)
{
    const int t = threadIdx.x;
    double s = 0.0;
#pragma unroll
    for (int i = 0; i < NBLK / 256; ++i) s += (double)partial[i * 256 + t];
    __shared__ double sd[256];
    sd[t] = s;
    __syncthreads();
    for (int off = 128; off > 0; off >>= 1) {
        if (t < off) sd[t] += sd[t + off];
        __syncthreads();
    }
    if (t == 0) {
        // out = total/(nc*M) - D*ln(256)
        out[0] = (float)(sd[0] * (1.0 / (double)(NC * M))
                         - (double)D * 5.545177444479562);
    }
}

extern "C" void kernel_launch(void* const* d_in, const int* in_sizes, int n_in,
                              void* d_out, int out_size, void* d_ws, size_t ws_size,
                              hipStream_t stream)
{
    const float* mean   = (const float*)d_in[0];
    const float* logvar = (const float*)d_in[1];
    const float* eps    = (const float*)d_in[2];
    float* out = (float*)d_out;

    float*  partial = (float*)d_ws;                       // NBLK floats = 4KB
    float4* params  = (float4*)((char*)d_ws + 4096);      // 512KB param table
    const bool use_gp = ws_size >= (size_t)4096 + sizeof(float4) * NC * D * AGG;

    if (use_gp) {
        ksetup<<<(NC * D * AGG) / 256, 256, 0, stream>>>(mean, logvar, params);
        kmain<true><<<NBLK, 256, 0, stream>>>(mean, logvar, eps, params, partial);
    } else {
        kmain<false><<<NBLK, 256, 0, stream>>>(mean, logvar, eps, nullptr, partial);
    }
    kfinal<<<1, 256, 0, stream>>>(partial, out);
}